// Round 6
// baseline (1742.178 us; speedup 1.0000x reference)
//
#include <hip/hip_runtime.h>
#include <math.h>

#define TB 256

typedef short bf16x8 __attribute__((ext_vector_type(8)));
typedef float f32x4 __attribute__((ext_vector_type(4)));
typedef unsigned short u16;

__device__ __forceinline__ float b2f(u16 u){
  union{unsigned int i; float f;} v; v.i = ((unsigned int)u)<<16; return v.f;
}
__device__ __forceinline__ u16 f2b(float f){
  union{float ff; unsigned int i;} v; v.ff=f;
  return (u16)((v.i + 0x7FFFu + ((v.i>>16)&1u))>>16);
}

// ---------------- prep kernels ----------------
__global__ void k_cvt(const float* __restrict__ s, u16* __restrict__ d, int n){
  int i = blockIdx.x*TB + threadIdx.x;
  if(i<n) d[i] = f2b(s[i]);
}

__global__ void k_bias(const float* __restrict__ table, float* __restrict__ out){
  int i = blockIdx.x*TB + threadIdx.x;            // [h][p][q], p=query q=key
  if(i >= 8*49*49) return;
  int h = i / 2401; int pq = i - h*2401; int p = pq/49; int q = pq - p*49;
  int pi=p/7, pj=p-pi*7, qi=q/7, qj=q-qi*7;
  int idx = (pi-qi+6)*13 + (pj-qj+6);
  out[i] = table[idx*8 + h];
}

// ---------------- fused LN1 + QKV + attention + proj + residual ----------------
// LDS map (bytes):
//   [0,32768)        region A: h_s bf16[64][256] swizzled
//   [32768,57856)    Q bf16 [8][49][32]  (pre-scaled by 8^-0.5); phase 3 reuses
//                    [32768,82944) as xt f32[49][256] (Q/K dead by then)
//   [57856,82944)    K bf16 [8][49][32]
//   [82944,108032)   V bf16 [8][49][32]
//   [108032,140800)  O bf16[64][256] swizzled
//   [140800,161280)  P scratch, 5120 B per wave
#define Q_OFF 32768
#define K_OFF 57856
#define V_OFF 82944
#define O_OFF 108032
#define P_OFF 140800
#define ATTN_LDS 161280

__global__ __launch_bounds__(256,1) void k_attn(
    const float* __restrict__ x,
    const u16* __restrict__ wqkv,
    const float* __restrict__ bqkv,
    const u16* __restrict__ wproj,
    const float* __restrict__ bproj,
    const float* __restrict__ biasm,
    const float* __restrict__ g1, const float* __restrict__ bt1,
    float* __restrict__ xg)           // = d_out, holds x2 fp32 in final [B,C,H,W] layout
{
  extern __shared__ char lds[];
  const int tid = threadIdx.x;
  const int wv = tid >> 6, l = tid & 63;
  const int lr = l & 15, lg = l >> 4;
  const unsigned swzl = ((unsigned)(lr & 7)) << 4;
  const int win = blockIdx.x;
  const int bb = win >> 6, wh = (win >> 3) & 7, ww = win & 7;
  const float* xwin = x + (size_t)bb*802816 + (size_t)wh*392 + ww*7;
  const size_t obase = (size_t)bb*802816 + (size_t)wh*392 + ww*7;

  // ---- phase 0: gather window + LN1 -> h_s (swizzled bf16), zero pad rows ----
  float gg[4], bgm[4];
  #pragma unroll
  for(int k2=0;k2<4;++k2){ gg[k2]=g1[l+64*k2]; bgm[k2]=bt1[l+64*k2]; }
  float xv[13][4];
  #pragma unroll
  for(int s=0;s<13;++s){
    int n = wv + s*4;
    if(n<49){
      int ii=n/7, jj=n-ii*7;
      const float* px = xwin + ii*56 + jj;
      #pragma unroll
      for(int k2=0;k2<4;++k2) xv[s][k2] = px[(size_t)(l+64*k2)*3136];
    }
  }
  #pragma unroll
  for(int s=0;s<13;++s){
    int n = wv + s*4;
    if(n<49){
      float sm=0.f, sq=0.f;
      #pragma unroll
      for(int k2=0;k2<4;++k2){ sm+=xv[s][k2]; sq+=xv[s][k2]*xv[s][k2]; }
      #pragma unroll
      for(int off=32;off>=1;off>>=1){ sm+=__shfl_xor(sm,off); sq+=__shfl_xor(sq,off); }
      float mu=sm*(1.f/256.f), var=sq*(1.f/256.f)-mu*mu;
      float rs=rsqrtf(var+1e-5f);
      #pragma unroll
      for(int k2=0;k2<4;++k2){
        int c=l+64*k2;
        unsigned off2 = (((unsigned)n)*512u + ((unsigned)c)*2u) ^ (((unsigned)(n&7))<<4);
        *(u16*)(lds + off2) = f2b((xv[s][k2]-mu)*rs*gg[k2]+bgm[k2]);
      }
    }
  }
  for(int m2=tid; m2<15*256; m2+=TB) *(u16*)(lds + 49*512 + m2*2) = 0;
  __syncthreads();

  // ---- phase 1: QKV GEMM (16x16x32 bf16 MFMA), scatter bf16 to Q/K/V ----
  u16* qb = (u16*)(lds + Q_OFF);
  u16* kb = (u16*)(lds + K_OFF);
  u16* vb = (u16*)(lds + V_OFF);

  for(int nt=wv; nt<48; nt+=4){
    bf16x8 bfr[8];
    const u16* wrow = wqkv + ((size_t)(nt*16+lr))*256 + lg*8;
    #pragma unroll
    for(int k=0;k<8;++k) bfr[k] = *(const bf16x8*)(wrow + k*32);
    const int cc = nt*16 + lr;
    const int s3 = cc>>8, hd=(cc>>5)&7, dd=cc&31;
    const float bc = bqkv[cc];
    #pragma unroll
    for(int mt=0; mt<4; ++mt){
      f32x4 acc = {0.f,0.f,0.f,0.f};
      #pragma unroll
      for(int k=0;k<8;++k){
        bf16x8 afr = *(const bf16x8*)(lds + ((((unsigned)(mt*16+lr))*512u + (unsigned)(k*64+lg*16)) ^ swzl));
        acc = __builtin_amdgcn_mfma_f32_16x16x32_bf16(afr, bfr[k], acc, 0,0,0);
      }
      #pragma unroll
      for(int i2=0;i2<4;++i2){
        int r = mt*16 + lg*4 + i2;
        if(r<49){
          float val = acc[i2] + bc;
          if(s3==0)      qb[hd*1568 + r*32 + dd] = f2b(val*0.35355339059327373f);
          else if(s3==1) kb[hd*1568 + r*32 + dd] = f2b(val);
          else           vb[hd*1568 + r*32 + dd] = f2b(val);
        }
      }
    }
  }
  __syncthreads();

  // ---- phase 2: attention, fp32 VALU. wave wv handles heads wv, wv+4 ----
  float oreg[2][32];
  u16* P = (u16*)(lds + P_OFF + wv*5120);
  const int lP = (l<49) ? l : 48;      // clamp: keep LDS reads in-bounds for pad lanes
  #pragma unroll
  for(int hh=0; hh<2; ++hh){
    const int h = wv + hh*4;
    float kr[32];
    {
      const u16* kp = kb + h*1568 + lP*32;
      #pragma unroll
      for(int m2=0;m2<4;++m2){
        bf16x8 kv = *(const bf16x8*)(kp + m2*8);
        #pragma unroll
        for(int e=0;e<8;++e) kr[m2*8+e] = b2f((u16)kv[e]);
      }
    }
    const float* bh = biasm + h*2401;
    for(int q=0;q<49;++q){
      const u16* qp = qb + h*1568 + q*32;     // broadcast across lanes
      float s = 0.f;
      #pragma unroll
      for(int m2=0;m2<4;++m2){
        bf16x8 qv = *(const bf16x8*)(qp + m2*8);
        #pragma unroll
        for(int e=0;e<8;++e) s += b2f((u16)qv[e]) * kr[m2*8+e];
      }
      s = (l<49) ? (s + bh[q*49+l]) : -1e30f;
      float mx=s;
      #pragma unroll
      for(int off=32;off>=1;off>>=1) mx=fmaxf(mx,__shfl_xor(mx,off));
      float p=expf(s-mx);
      float su=p;
      #pragma unroll
      for(int off=32;off>=1;off>>=1) su+=__shfl_xor(su,off);
      if(l<49) P[q*52+l]=f2b(p/su);
    }
    __syncthreads();
    #pragma unroll
    for(int d=0;d<32;++d) oreg[hh][d]=0.f;
    const u16* vh = vb + h*1568;
    for(int j=0;j<49;++j){
      float p = b2f(P[lP*52+j]);
      #pragma unroll
      for(int m2=0;m2<4;++m2){
        bf16x8 vv = *(const bf16x8*)(vh + j*32 + m2*8);
        #pragma unroll
        for(int e=0;e<8;++e) oreg[hh][m2*8+e] += p*b2f((u16)vv[e]);
      }
    }
    __syncthreads();
  }

  // ---- write O tiles (swizzled bf16 [64][256] at O_OFF), zero pad rows ----
  if(l<49){
    #pragma unroll
    for(int hh=0; hh<2; ++hh){
      const int h = wv + hh*4;
      #pragma unroll
      for(int ch=0; ch<4; ++ch){
        bf16x8 pk;
        #pragma unroll
        for(int e=0;e<8;++e) pk[e]=(short)f2b(oreg[hh][ch*8+e]);
        *(bf16x8*)(lds + O_OFF + ((((unsigned)l)*512u + (unsigned)(h*64 + ch*16)) ^ (((unsigned)(l&7))<<4))) = pk;
      }
    }
  }
  for(int m2=tid; m2<15*256; m2+=TB) *(u16*)(lds + O_OFF + 49*512 + m2*2) = 0;
  __syncthreads();

  // ---- phase 3: proj GEMM + residual -> xt f32[49][256] (over dead Q/K region) ----
  float* xtf = (float*)(lds + Q_OFF);
  for(int nt=wv; nt<16; nt+=4){
    bf16x8 bfr[8];
    const u16* wrow = wproj + ((size_t)(nt*16+lr))*256 + lg*8;
    #pragma unroll
    for(int k=0;k<8;++k) bfr[k]=*(const bf16x8*)(wrow + k*32);
    const int c = nt*16+lr;
    const float pb = bproj[c];
    #pragma unroll
    for(int mt=0; mt<4; ++mt){
      f32x4 acc={0.f,0.f,0.f,0.f};
      #pragma unroll
      for(int k=0;k<8;++k){
        bf16x8 afr = *(const bf16x8*)(lds + O_OFF + ((((unsigned)(mt*16+lr))*512u + (unsigned)(k*64+lg*16)) ^ swzl));
        acc = __builtin_amdgcn_mfma_f32_16x16x32_bf16(afr, bfr[k], acc, 0,0,0);
      }
      #pragma unroll
      for(int i2=0;i2<4;++i2){
        int r = mt*16 + lg*4 + i2;
        if(r<49){
          int ii=r/7, jj2=r-ii*7;
          xtf[r*256 + c] = acc[i2] + pb + xwin[(size_t)c*3136 + ii*56 + jj2];
        }
      }
    }
  }
  __syncthreads();

  // ---- writeout: scatter xt fp32 to d_out in final [B,C,H,W] layout ----
  for(int u=tid; u<1792; u+=TB){
    int c = u/7, i = u - (u/7)*7;
    float* dst = xg + obase + (size_t)c*3136 + i*56;
    #pragma unroll
    for(int j=0;j<7;++j) dst[j] = xtf[(i*7+j)*256 + c];
  }
}

// ---------------- fused LN2 + MLP + residual, in-place on d_out (fp32) ----------------
// LDS: [0,32768) h2s swz bf16[64][256]; [32768,65536) hids swz bf16[64][256];
//      [65536,131072) xt f32[64][256] linear
#define MLP_XT 65536
#define MLP_LDS 131072

__global__ __launch_bounds__(256,1) void k_mlp(
    float* __restrict__ xg,           // = d_out (read x2 fp32, write final fp32)
    const u16* __restrict__ w1, const float* __restrict__ b1v,
    const u16* __restrict__ w2, const float* __restrict__ b2v,
    const float* __restrict__ g2, const float* __restrict__ bt2)
{
  extern __shared__ char lds[];
  const int tid = threadIdx.x;
  const int wv = tid >> 6, l = tid & 63;
  const int lr = l & 15, lg = l >> 4;
  const unsigned swzl = ((unsigned)(lr & 7)) << 4;
  const int win = blockIdx.x;
  const int bb = win >> 6, wh = (win >> 3) & 7, ww = win & 7;
  const size_t obase = (size_t)bb*802816 + (size_t)wh*392 + ww*7;
  float* xt = (float*)(lds + MLP_XT);

  // ---- gather x2 tile fp32 from d_out; zero pad rows ----
  for(int m=tid; m<15*256; m+=TB) xt[49*256+m] = 0.f;
  for(int u=tid; u<1792; u+=TB){
    int c = u/7, i = u - (u/7)*7;
    const float* src = xg + obase + (size_t)c*3136 + i*56;
    #pragma unroll
    for(int j=0;j<7;++j) xt[(i*7+j)*256 + c] = src[j];
  }
  __syncthreads();

  // ---- LN2 -> h2s (swizzled bf16) ----
  {
    float gg[4], bb2[4];
    #pragma unroll
    for(int k2=0;k2<4;++k2){ gg[k2]=g2[l+64*k2]; bb2[k2]=bt2[l+64*k2]; }
    for(int rr=0; rr<16; ++rr){
      int r = wv*16 + rr;
      float v[4];
      #pragma unroll
      for(int k2=0;k2<4;++k2) v[k2]=xt[r*256 + l + 64*k2];
      float sm=v[0]+v[1]+v[2]+v[3];
      float sq=v[0]*v[0]+v[1]*v[1]+v[2]*v[2]+v[3]*v[3];
      #pragma unroll
      for(int off=32;off>=1;off>>=1){ sm+=__shfl_xor(sm,off); sq+=__shfl_xor(sq,off); }
      float mu=sm*(1.f/256.f), var=sq*(1.f/256.f)-mu*mu, rs=rsqrtf(var+1e-5f);
      #pragma unroll
      for(int k2=0;k2<4;++k2){
        int c=l+64*k2;
        unsigned off2 = (((unsigned)r)*512u + ((unsigned)c)*2u) ^ (((unsigned)(r&7))<<4);
        *(u16*)(lds + off2) = f2b((v[k2]-mu)*rs*gg[k2]+bb2[k2]);
      }
    }
  }
  __syncthreads();

  f32x4 acc2[4][4];
  #pragma unroll
  for(int a3=0;a3<4;++a3)
    #pragma unroll
    for(int b3=0;b3<4;++b3) acc2[a3][b3]=(f32x4){0.f,0.f,0.f,0.f};

  for(int kc=0; kc<4; ++kc){
    // GEMM1 + GELU -> hids
    #pragma unroll
    for(int nt1=0; nt1<4; ++nt1){
      const int gcol = kc*256 + wv*64 + nt1*16 + lr;
      bf16x8 bfr[8];
      const u16* wrow = w1 + (size_t)gcol*256 + lg*8;
      #pragma unroll
      for(int k=0;k<8;++k) bfr[k]=*(const bf16x8*)(wrow + k*32);
      const float bias1 = b1v[gcol];
      #pragma unroll
      for(int mt=0; mt<4; ++mt){
        f32x4 acc={0.f,0.f,0.f,0.f};
        #pragma unroll
        for(int k=0;k<8;++k){
          bf16x8 afr = *(const bf16x8*)(lds + ((((unsigned)(mt*16+lr))*512u + (unsigned)(k*64+lg*16)) ^ swzl));
          acc = __builtin_amdgcn_mfma_f32_16x16x32_bf16(afr, bfr[k], acc, 0,0,0);
        }
        #pragma unroll
        for(int i2=0;i2<4;++i2){
          int r = mt*16 + lg*4 + i2;
          float vv = acc[i2] + bias1;
          float gl = 0.5f*vv*(1.f + erff(vv*0.70710678118654752f));
          unsigned off2 = 32768u + ((((unsigned)r)*512u + (unsigned)((wv*64+nt1*16+lr)*2)) ^ (((unsigned)(r&7))<<4));
          *(u16*)(lds + off2) = f2b(gl);
        }
      }
    }
    __syncthreads();
    // GEMM2 accumulate
    #pragma unroll
    for(int nt2=0; nt2<4; ++nt2){
      const int c = wv*64 + nt2*16 + lr;
      bf16x8 bfr[8];
      const u16* wrow = w2 + (size_t)c*1024 + kc*256 + lg*8;
      #pragma unroll
      for(int k=0;k<8;++k) bfr[k]=*(const bf16x8*)(wrow + k*32);
      #pragma unroll
      for(int mt=0; mt<4; ++mt){
        f32x4 a4 = acc2[nt2][mt];
        #pragma unroll
        for(int k=0;k<8;++k){
          bf16x8 afr = *(const bf16x8*)(lds + (32768u + ((((unsigned)(mt*16+lr))*512u + (unsigned)(k*64+lg*16)) ^ swzl)));
          a4 = __builtin_amdgcn_mfma_f32_16x16x32_bf16(afr, bfr[k], a4, 0,0,0);
        }
        acc2[nt2][mt] = a4;
      }
    }
    __syncthreads();
  }

  // ---- epilogue: +b2 +residual fp32, update xt in place ----
  #pragma unroll
  for(int nt2=0; nt2<4; ++nt2){
    const int c = wv*64 + nt2*16 + lr;
    const float biasc = b2v[c];
    #pragma unroll
    for(int mt=0; mt<4; ++mt){
      #pragma unroll
      for(int i2=0;i2<4;++i2){
        int r = mt*16 + lg*4 + i2;
        xt[r*256 + c] = acc2[nt2][mt][i2] + biasc + xt[r*256 + c];
      }
    }
  }
  __syncthreads();

  // ---- writeout final fp32 to d_out ----
  for(int u=tid; u<1792; u+=TB){
    int c = u/7, i = u - (u/7)*7;
    float* dst = xg + obase + (size_t)c*3136 + i*56;
    #pragma unroll
    for(int j=0;j<7;++j) dst[j] = xt[(i*7+j)*256 + c];
  }
}

extern "C" void kernel_launch(void* const* d_in, const int* in_sizes, int n_in,
                              void* d_out, int out_size, void* d_ws, size_t ws_size,
                              hipStream_t stream) {
  const float* x      = (const float*)d_in[0];
  const float* qkv_w  = (const float*)d_in[1];
  const float* qkv_b  = (const float*)d_in[2];
  const float* proj_w = (const float*)d_in[3];
  const float* proj_b = (const float*)d_in[4];
  const float* btab   = (const float*)d_in[5];
  const float* ln1g   = (const float*)d_in[6];
  const float* ln1b   = (const float*)d_in[7];
  const float* ln2g   = (const float*)d_in[8];
  const float* ln2b   = (const float*)d_in[9];
  const float* w1     = (const float*)d_in[10];
  const float* b1     = (const float*)d_in[11];
  const float* w2     = (const float*)d_in[12];
  const float* b2     = (const float*)d_in[13];

  char* ws = (char*)d_ws;
  float* biasm = (float*)ws;                     // 76,832 B (reserve 128K)
  u16*   wq    = (u16*)(ws + 131072);            // 393,216 B
  u16*   wp    = (u16*)(ws + 524288);            // 131,072 B
  u16*   w1b   = (u16*)(ws + 655360);            // 524,288 B
  u16*   w2b   = (u16*)(ws + 1179648);           // 524,288 B  -> total 1,703,936 B

  k_cvt<<<196608/TB, TB, 0, stream>>>(qkv_w, wq, 196608);
  k_cvt<<<65536/TB,  TB, 0, stream>>>(proj_w, wp, 65536);
  k_cvt<<<262144/TB, TB, 0, stream>>>(w1, w1b, 262144);
  k_cvt<<<262144/TB, TB, 0, stream>>>(w2, w2b, 262144);
  k_bias<<<(8*49*49+TB-1)/TB, TB, 0, stream>>>(btab, biasm);

  hipFuncSetAttribute((const void*)k_attn, hipFuncAttributeMaxDynamicSharedMemorySize, ATTN_LDS);
  hipFuncSetAttribute((const void*)k_mlp,  hipFuncAttributeMaxDynamicSharedMemorySize, MLP_LDS);
  k_attn<<<2048, TB, ATTN_LDS, stream>>>(x, wq, qkv_b, wp, proj_b, biasm, ln1g, ln1b, (float*)d_out);
  k_mlp <<<2048, TB, MLP_LDS,  stream>>>((float*)d_out, w1b, b1, w2b, b2, ln2g, ln2b);
}

// Round 7
// 1067.811 us; speedup vs baseline: 1.6315x; 1.6315x over previous
//
#include <hip/hip_runtime.h>
#include <math.h>

#define TB 256

typedef short bf16x8 __attribute__((ext_vector_type(8)));
typedef short s16x4 __attribute__((ext_vector_type(4)));
typedef float f32x4 __attribute__((ext_vector_type(4)));
typedef unsigned short u16;

__device__ __forceinline__ float b2f(u16 u){
  union{unsigned int i; float f;} v; v.i = ((unsigned int)u)<<16; return v.f;
}
__device__ __forceinline__ u16 f2b(float f){
  union{float ff; unsigned int i;} v; v.ff=f;
  return (u16)((v.i + 0x7FFFu + ((v.i>>16)&1u))>>16);
}

// ---------------- prep kernels ----------------
__global__ void k_cvt(const float* __restrict__ s, u16* __restrict__ d, int n){
  int i = blockIdx.x*TB + threadIdx.x;
  if(i<n) d[i] = f2b(s[i]);
}

// bias_t[h][k][64 q] f32, padded to 64x64 with zeros. biasT[h][k][q] = bias[h][q(query)][k(key)]
__global__ void k_biasT(const float* __restrict__ table, float* __restrict__ out){
  int i = blockIdx.x*TB + threadIdx.x;
  if(i >= 8*64*64) return;
  int h = i>>12, kq = i&4095, k = kq>>6, q = kq&63;
  float v = 0.f;
  if(k<49 && q<49){
    int qi=q/7, qj=q-qi*7, ki=k/7, kj=k-ki*7;
    int idx = (qi-ki+6)*13 + (qj-kj+6);
    v = table[idx*8+h];
  }
  out[i] = v;
}

// ---------------- fused LN1 + QKV + MFMA attention + proj + residual ----------------
// LDS (bytes), 131072 total:
//   [0,32768)       A: h_s bf16[64][256] swz(row&7)   -> P waves 0-3 -> xt f32 (lo)
//   [32768,65536)   Qbuf bf16[8][64][32] swz((r>>2)&3)-> P waves 4-7 -> xt f32 (hi)
//   [65536,98304)   Kbuf bf16[8][64][32] swz          -> O bf16[8][64][32] swz
//   [98304,131072)  Vt  bf16[8][32][64] swz(d&7)      (pads zeroed)
#define QB_OFF 32768
#define KB_OFF 65536
#define VT_OFF 98304
#define ATTN_LDS 131072

__global__ __launch_bounds__(512,1) void k_attn(
    const float* __restrict__ x,
    const u16* __restrict__ wqkv,
    const float* __restrict__ bqkv,
    const u16* __restrict__ wproj,
    const float* __restrict__ bproj,
    const float* __restrict__ biasT,
    const float* __restrict__ g1, const float* __restrict__ bt1,
    float* __restrict__ xg)           // = d_out, x2 fp32 in final [B,C,H,W] layout
{
  extern __shared__ char lds[];
  const int tid = threadIdx.x;
  const int wv = tid >> 6, l = tid & 63;
  const int lr = l & 15, lg = l >> 4;
  const unsigned swzA = ((unsigned)(lr & 7)) << 4;       // 512B-row + 128B-row buffers
  const unsigned swzR = ((unsigned)((lr>>2) & 3)) << 4;  // 64B-row buffers (Q,K,O)
  const int win = blockIdx.x;
  const int bb = win >> 6, wh = (win >> 3) & 7, ww = win & 7;
  const float* xwin = x + (size_t)bb*802816 + (size_t)wh*392 + ww*7;
  const size_t obase = (size_t)bb*802816 + (size_t)wh*392 + ww*7;

  // ---- phase 0: gather + LN1 -> h_s; zero h_s pad rows and all of Vt ----
  {
    float gg[4], bgm[4];
    #pragma unroll
    for(int k2=0;k2<4;++k2){ gg[k2]=g1[l+64*k2]; bgm[k2]=bt1[l+64*k2]; }
    float xv[7][4];
    #pragma unroll
    for(int s=0;s<7;++s){
      int n = wv + s*8;
      if(n<49){
        int ii=n/7, jj=n-ii*7;
        const float* px = xwin + ii*56 + jj;
        #pragma unroll
        for(int k2=0;k2<4;++k2) xv[s][k2] = px[(size_t)(l+64*k2)*3136];
      }
    }
    #pragma unroll
    for(int s=0;s<7;++s){
      int n = wv + s*8;
      if(n<49){
        float sm=0.f, sq=0.f;
        #pragma unroll
        for(int k2=0;k2<4;++k2){ sm+=xv[s][k2]; sq+=xv[s][k2]*xv[s][k2]; }
        #pragma unroll
        for(int off=32;off>=1;off>>=1){ sm+=__shfl_xor(sm,off); sq+=__shfl_xor(sq,off); }
        float mu=sm*(1.f/256.f), var=sq*(1.f/256.f)-mu*mu;
        float rs=rsqrtf(var+1e-5f);
        #pragma unroll
        for(int k2=0;k2<4;++k2){
          int c=l+64*k2;
          unsigned off2 = (((unsigned)n)*512u + ((unsigned)c)*2u) ^ (((unsigned)(n&7))<<4);
          *(u16*)(lds + off2) = f2b((xv[s][k2]-mu)*rs*gg[k2]+bgm[k2]);
        }
      }
    }
  }
  for(int m=tid; m<3840; m+=512) *(u16*)(lds + 49*512 + m*2) = 0;
  for(int m=tid; m<8192; m+=512) *(unsigned*)(lds + VT_OFF + m*4) = 0u;
  __syncthreads();

  // ---- phase 1: QKV GEMM, transposed output D[c][r]; scatter to Qbuf/Kbuf/Vt ----
  for(int ct=wv; ct<48; ct+=8){
    bf16x8 bfr[8];
    const u16* wrow = wqkv + ((size_t)(ct*16+lr))*256 + lg*8;
    #pragma unroll
    for(int k=0;k<8;++k) bfr[k] = *(const bf16x8*)(wrow + k*32);
    f32x4 b4 = *(const f32x4*)(bqkv + ct*16 + lg*4);
    const int s3 = ct>>4, hd = (ct>>1)&7, db = (ct&1)*16 + lg*4;
    #pragma unroll
    for(int rt=0; rt<4; ++rt){
      f32x4 acc = {0.f,0.f,0.f,0.f};
      #pragma unroll
      for(int k=0;k<8;++k){
        bf16x8 afr = *(const bf16x8*)(lds + ((((unsigned)(rt*16+lr))*512u + (unsigned)(k*64+lg*16)) ^ swzA));
        acc = __builtin_amdgcn_mfma_f32_16x16x32_bf16(bfr[k], afr, acc, 0,0,0);
      }
      const int r = rt*16 + lr;
      if(r<49){
        if(s3==0){
          s16x4 pk;
          #pragma unroll
          for(int i=0;i<4;++i) pk[i] = (short)f2b((acc[i]+b4[i])*0.35355339059327373f);
          *(s16x4*)(lds + ((unsigned)(QB_OFF + hd*4096 + r*64 + db*2) ^ swzR)) = pk;
        } else if(s3==1){
          s16x4 pk;
          #pragma unroll
          for(int i=0;i<4;++i) pk[i] = (short)f2b(acc[i]+b4[i]);
          *(s16x4*)(lds + ((unsigned)(KB_OFF + hd*4096 + r*64 + db*2) ^ swzR)) = pk;
        } else {
          #pragma unroll
          for(int i=0;i<4;++i)
            *(u16*)(lds + ((unsigned)(VT_OFF + hd*4096 + (db+i)*128 + r*2) ^ ((((unsigned)(db+i))&7u)<<4))) = f2b(acc[i]+b4[i]);
        }
      }
    }
  }
  __syncthreads();

  // ---- phase 2a: S^T = mfma(K,Q)+biasC, mask, softmax -> packed P in regs ----
  const int h = wv;
  bf16x8 kf[4], qf[4];
  #pragma unroll
  for(int t=0;t<4;++t){
    kf[t] = *(const bf16x8*)(lds + ((unsigned)(KB_OFF + h*4096 + (t*16+lr)*64 + lg*16) ^ swzR));
    qf[t] = *(const bf16x8*)(lds + ((unsigned)(QB_OFF + h*4096 + (t*16+lr)*64 + lg*16) ^ swzR));
  }
  f32x4 st[4][4];
  #pragma unroll
  for(int qt=0;qt<4;++qt)
    #pragma unroll
    for(int kt=0;kt<4;++kt){
      f32x4 bini;
      #pragma unroll
      for(int i=0;i<4;++i) bini[i] = biasT[h*4096 + (kt*16+lg*4+i)*64 + qt*16+lr];
      st[qt][kt] = __builtin_amdgcn_mfma_f32_16x16x32_bf16(kf[kt], qf[qt], bini, 0,0,0);
    }
  #pragma unroll
  for(int qt=0;qt<4;++qt)
    #pragma unroll
    for(int i=0;i<4;++i)
      if(!(lg==0 && i==0)) st[qt][3][i] = -1e30f;   // only k=48 valid in kt=3 tile

  s16x4 pk[4][4];
  #pragma unroll
  for(int qt=0;qt<4;++qt){
    float mx = -1e30f;
    #pragma unroll
    for(int kt=0;kt<4;++kt)
      #pragma unroll
      for(int i=0;i<4;++i) mx = fmaxf(mx, st[qt][kt][i]);
    mx = fmaxf(mx, __shfl_xor(mx,16));
    mx = fmaxf(mx, __shfl_xor(mx,32));
    float su = 0.f;
    #pragma unroll
    for(int kt=0;kt<4;++kt)
      #pragma unroll
      for(int i=0;i<4;++i){ float p = __expf(st[qt][kt][i]-mx); st[qt][kt][i]=p; su+=p; }
    su += __shfl_xor(su,16);
    su += __shfl_xor(su,32);
    float inv = 1.f/su;
    #pragma unroll
    for(int kt=0;kt<4;++kt)
      #pragma unroll
      for(int i=0;i<4;++i) pk[qt][kt][i] = (short)f2b(st[qt][kt][i]*inv);
  }
  __syncthreads();        // all S^T reads of Qbuf done -> Qbuf/A reusable as P

  // ---- phase 2b/2c: write P; PV = mfma(P, V^T) -> O into Kbuf ----
  char* Pb = lds + wv*8192;     // waves 0-3 in A, 4-7 in Qbuf (contiguous [0,64K))
  #pragma unroll
  for(int qt=0;qt<4;++qt)
    #pragma unroll
    for(int kt=0;kt<4;++kt)
      *(s16x4*)(Pb + ((((unsigned)(qt*16+lr))*128u + (unsigned)(kt*32+lg*8)) ^ swzA)) = pk[qt][kt];

  bf16x8 pf[4][2], vf[2][2];
  #pragma unroll
  for(int qt=0;qt<4;++qt)
    #pragma unroll
    for(int ks=0;ks<2;++ks)
      pf[qt][ks] = *(const bf16x8*)(Pb + ((((unsigned)(qt*16+lr))*128u + (unsigned)(ks*64+lg*16)) ^ swzA));
  #pragma unroll
  for(int dt=0;dt<2;++dt)
    #pragma unroll
    for(int ks=0;ks<2;++ks)
      vf[dt][ks] = *(const bf16x8*)(lds + ((unsigned)(VT_OFF + h*4096 + (dt*16+lr)*128 + ks*64+lg*16) ^ swzA));
  #pragma unroll
  for(int qt=0;qt<4;++qt)
    #pragma unroll
    for(int dt=0;dt<2;++dt){
      f32x4 o = {0.f,0.f,0.f,0.f};
      o = __builtin_amdgcn_mfma_f32_16x16x32_bf16(pf[qt][0], vf[dt][0], o, 0,0,0);
      o = __builtin_amdgcn_mfma_f32_16x16x32_bf16(pf[qt][1], vf[dt][1], o, 0,0,0);
      #pragma unroll
      for(int i=0;i<4;++i)
        *(u16*)(lds + ((unsigned)(KB_OFF + h*4096 + (qt*16+lg*4+i)*64 + (dt*16+lr)*2) ^ (((unsigned)lg)<<4))) = f2b(o[i]);
    }
  __syncthreads();        // O complete; P dead -> [0,64K) free for xt

  // ---- phase 3: proj GEMM + residual -> xt f32[64][256] at lds[0,64K) ----
  float* xtf = (float*)lds;
  for(int nt=wv; nt<16; nt+=8){
    bf16x8 bfr[8];
    const u16* wrow = wproj + ((size_t)(nt*16+lr))*256 + lg*8;
    #pragma unroll
    for(int k=0;k<8;++k) bfr[k] = *(const bf16x8*)(wrow + k*32);
    const int c = nt*16 + lr;
    const float pb = bproj[c];
    #pragma unroll
    for(int mt=0; mt<4; ++mt){
      f32x4 acc = {0.f,0.f,0.f,0.f};
      #pragma unroll
      for(int ks=0;ks<8;++ks){
        bf16x8 afr = *(const bf16x8*)(lds + ((unsigned)(KB_OFF + ks*4096 + (mt*16+lr)*64 + lg*16) ^ swzR));
        acc = __builtin_amdgcn_mfma_f32_16x16x32_bf16(afr, bfr[ks], acc, 0,0,0);
      }
      #pragma unroll
      for(int i=0;i<4;++i){
        int r = mt*16 + lg*4 + i;
        if(r<49){
          int ii=r/7, jj=r-ii*7;
          xtf[r*256 + c] = acc[i] + pb + xwin[(size_t)c*3136 + ii*56 + jj];
        }
      }
    }
  }
  __syncthreads();

  // ---- writeout: scatter fp32 to d_out in [B,C,H,W] layout ----
  for(int u=tid; u<1792; u+=512){
    int c = u/7, i = u - (u/7)*7;
    float* dst = xg + obase + (size_t)c*3136 + i*56;
    #pragma unroll
    for(int j=0;j<7;++j) dst[j] = xtf[(i*7+j)*256 + c];
  }
}

// ---------------- fused LN2 + MLP + residual, in-place on d_out (fp32) ----------------
// LDS: [0,32768) h2s swz bf16[64][256]; [32768,65536) hids swz bf16[64][256];
//      [65536,131072) xt f32[64][256]
#define MLP_XT 65536
#define MLP_LDS 131072

__global__ __launch_bounds__(512,1) void k_mlp(
    float* __restrict__ xg,
    const u16* __restrict__ w1, const float* __restrict__ b1v,
    const u16* __restrict__ w2, const float* __restrict__ b2v,
    const float* __restrict__ g2, const float* __restrict__ bt2)
{
  extern __shared__ char lds[];
  const int tid = threadIdx.x;
  const int wv = tid >> 6, l = tid & 63;
  const int lr = l & 15, lg = l >> 4;
  const unsigned swzA = ((unsigned)(lr & 7)) << 4;
  const int win = blockIdx.x;
  const int bb = win >> 6, wh = (win >> 3) & 7, ww = win & 7;
  const size_t obase = (size_t)bb*802816 + (size_t)wh*392 + ww*7;
  float* xt = (float*)(lds + MLP_XT);

  // ---- gather x2 fp32 tile; zero pad rows ----
  for(int m=tid; m<3840; m+=512) xt[49*256+m] = 0.f;
  for(int u=tid; u<1792; u+=512){
    int c = u/7, i = u - (u/7)*7;
    const float* src = xg + obase + (size_t)c*3136 + i*56;
    #pragma unroll
    for(int j=0;j<7;++j) xt[(i*7+j)*256 + c] = src[j];
  }
  __syncthreads();

  // ---- LN2 -> h2s ----
  {
    float gg[4], bb2[4];
    #pragma unroll
    for(int k2=0;k2<4;++k2){ gg[k2]=g2[l+64*k2]; bb2[k2]=bt2[l+64*k2]; }
    #pragma unroll
    for(int rr=0; rr<8; ++rr){
      int r = wv*8 + rr;
      float v[4];
      #pragma unroll
      for(int k2=0;k2<4;++k2) v[k2]=xt[r*256 + l + 64*k2];
      float sm=v[0]+v[1]+v[2]+v[3];
      float sq=v[0]*v[0]+v[1]*v[1]+v[2]*v[2]+v[3]*v[3];
      #pragma unroll
      for(int off=32;off>=1;off>>=1){ sm+=__shfl_xor(sm,off); sq+=__shfl_xor(sq,off); }
      float mu=sm*(1.f/256.f), var=sq*(1.f/256.f)-mu*mu, rs=rsqrtf(var+1e-5f);
      #pragma unroll
      for(int k2=0;k2<4;++k2){
        int c=l+64*k2;
        unsigned off2 = (((unsigned)r)*512u + ((unsigned)c)*2u) ^ (((unsigned)(r&7))<<4);
        *(u16*)(lds + off2) = f2b((v[k2]-mu)*rs*gg[k2]+bb2[k2]);
      }
    }
  }
  __syncthreads();

  f32x4 acc2[2][4];
  #pragma unroll
  for(int a3=0;a3<2;++a3)
    #pragma unroll
    for(int b3=0;b3<4;++b3) acc2[a3][b3]=(f32x4){0.f,0.f,0.f,0.f};

  for(int kc=0; kc<4; ++kc){
    // GEMM1 + GELU -> hids
    #pragma unroll
    for(int nt1=0; nt1<2; ++nt1){
      const int hcol = wv*32 + nt1*16 + lr;
      const int gcol = kc*256 + hcol;
      bf16x8 bfr[8];
      const u16* wrow = w1 + (size_t)gcol*256 + lg*8;
      #pragma unroll
      for(int k=0;k<8;++k) bfr[k]=*(const bf16x8*)(wrow + k*32);
      const float bias1 = b1v[gcol];
      #pragma unroll
      for(int mt=0; mt<4; ++mt){
        f32x4 acc={0.f,0.f,0.f,0.f};
        #pragma unroll
        for(int k=0;k<8;++k){
          bf16x8 afr = *(const bf16x8*)(lds + ((((unsigned)(mt*16+lr))*512u + (unsigned)(k*64+lg*16)) ^ swzA));
          acc = __builtin_amdgcn_mfma_f32_16x16x32_bf16(afr, bfr[k], acc, 0,0,0);
        }
        #pragma unroll
        for(int i2=0;i2<4;++i2){
          int r = mt*16 + lg*4 + i2;
          float vv = acc[i2] + bias1;
          float gl = 0.5f*vv*(1.f + erff(vv*0.70710678118654752f));
          unsigned off2 = 32768u + ((((unsigned)r)*512u + ((unsigned)hcol)*2u) ^ (((unsigned)(r&7))<<4));
          *(u16*)(lds + off2) = f2b(gl);
        }
      }
    }
    __syncthreads();
    // GEMM2 accumulate
    #pragma unroll
    for(int nt2=0; nt2<2; ++nt2){
      const int c = wv*32 + nt2*16 + lr;
      bf16x8 bfr[8];
      const u16* wrow = w2 + (size_t)c*1024 + kc*256 + lg*8;
      #pragma unroll
      for(int k=0;k<8;++k) bfr[k]=*(const bf16x8*)(wrow + k*32);
      #pragma unroll
      for(int mt=0; mt<4; ++mt){
        f32x4 a4 = acc2[nt2][mt];
        #pragma unroll
        for(int k=0;k<8;++k){
          bf16x8 afr = *(const bf16x8*)(lds + (32768u + ((((unsigned)(mt*16+lr))*512u + (unsigned)(k*64+lg*16)) ^ swzA)));
          a4 = __builtin_amdgcn_mfma_f32_16x16x32_bf16(afr, bfr[k], a4, 0,0,0);
        }
        acc2[nt2][mt] = a4;
      }
    }
    __syncthreads();
  }

  // ---- epilogue: +b2 +residual fp32 ----
  #pragma unroll
  for(int nt2=0; nt2<2; ++nt2){
    const int c = wv*32 + nt2*16 + lr;
    const float biasc = b2v[c];
    #pragma unroll
    for(int mt=0; mt<4; ++mt){
      #pragma unroll
      for(int i2=0;i2<4;++i2){
        int r = mt*16 + lg*4 + i2;
        xt[r*256 + c] = acc2[nt2][mt][i2] + biasc + xt[r*256 + c];
      }
    }
  }
  __syncthreads();

  // ---- writeout fp32 ----
  for(int u=tid; u<1792; u+=512){
    int c = u/7, i = u - (u/7)*7;
    float* dst = xg + obase + (size_t)c*3136 + i*56;
    #pragma unroll
    for(int j=0;j<7;++j) dst[j] = xt[(i*7+j)*256 + c];
  }
}

extern "C" void kernel_launch(void* const* d_in, const int* in_sizes, int n_in,
                              void* d_out, int out_size, void* d_ws, size_t ws_size,
                              hipStream_t stream) {
  const float* x      = (const float*)d_in[0];
  const float* qkv_w  = (const float*)d_in[1];
  const float* qkv_b  = (const float*)d_in[2];
  const float* proj_w = (const float*)d_in[3];
  const float* proj_b = (const float*)d_in[4];
  const float* btab   = (const float*)d_in[5];
  const float* ln1g   = (const float*)d_in[6];
  const float* ln1b   = (const float*)d_in[7];
  const float* ln2g   = (const float*)d_in[8];
  const float* ln2b   = (const float*)d_in[9];
  const float* w1     = (const float*)d_in[10];
  const float* b1     = (const float*)d_in[11];
  const float* w2     = (const float*)d_in[12];
  const float* b2     = (const float*)d_in[13];

  char* ws = (char*)d_ws;
  float* biasT = (float*)ws;                     // 131,072 B
  u16*   wq    = (u16*)(ws + 131072);            // 393,216 B
  u16*   wp    = (u16*)(ws + 524288);            // 131,072 B
  u16*   w1b   = (u16*)(ws + 655360);            // 524,288 B
  u16*   w2b   = (u16*)(ws + 1179648);           // 524,288 B -> total 1,703,936 B

  k_cvt<<<196608/TB, TB, 0, stream>>>(qkv_w, wq, 196608);
  k_cvt<<<65536/TB,  TB, 0, stream>>>(proj_w, wp, 65536);
  k_cvt<<<262144/TB, TB, 0, stream>>>(w1, w1b, 262144);
  k_cvt<<<262144/TB, TB, 0, stream>>>(w2, w2b, 262144);
  k_biasT<<<32768/TB, TB, 0, stream>>>(btab, biasT);

  hipFuncSetAttribute((const void*)k_attn, hipFuncAttributeMaxDynamicSharedMemorySize, ATTN_LDS);
  hipFuncSetAttribute((const void*)k_mlp,  hipFuncAttributeMaxDynamicSharedMemorySize, MLP_LDS);
  k_attn<<<2048, 512, ATTN_LDS, stream>>>(x, wq, qkv_b, wp, proj_b, biasT, ln1g, ln1b, (float*)d_out);
  k_mlp <<<2048, 512, MLP_LDS,  stream>>>((float*)d_out, w1b, b1, w2b, b2, ln2g, ln2b);
}

// Round 8
// 877.990 us; speedup vs baseline: 1.9843x; 1.2162x over previous
//
#include <hip/hip_runtime.h>
#include <math.h>

#define TB 256

typedef short bf16x8 __attribute__((ext_vector_type(8)));
typedef short s16x4 __attribute__((ext_vector_type(4)));
typedef float f32x4 __attribute__((ext_vector_type(4)));
typedef unsigned short u16;

__device__ __forceinline__ float b2f(u16 u){
  union{unsigned int i; float f;} v; v.i = ((unsigned int)u)<<16; return v.f;
}
__device__ __forceinline__ u16 f2b(float f){
  union{float ff; unsigned int i;} v; v.ff=f;
  return (u16)((v.i + 0x7FFFu + ((v.i>>16)&1u))>>16);
}

// ---------------- prep kernels ----------------
__global__ void k_cvt(const float* __restrict__ s, u16* __restrict__ d, int n){
  int i = blockIdx.x*TB + threadIdx.x;
  if(i<n) d[i] = f2b(s[i]);
}

// biasT[h][k][q] f32 (64x64 padded with zeros) = bias[h][q][k]
__global__ void k_biasT(const float* __restrict__ table, float* __restrict__ out){
  int i = blockIdx.x*TB + threadIdx.x;
  if(i >= 8*64*64) return;
  int h = i>>12, kq = i&4095, k = kq>>6, q = kq&63;
  float v = 0.f;
  if(k<49 && q<49){
    int qi=q/7, qj=q-qi*7, ki=k/7, kj=k-ki*7;
    int idx = (qi-ki+6)*13 + (qj-kj+6);
    v = table[idx*8+h];
  }
  out[i] = v;
}

// ---------------- fully fused transformer block, 1 window / block ----------------
// 1024 threads (16 waves), 128 KB dynamic LDS. Region timeline:
//   [0,32768)       h_s bf16[64][256] swz(r&7)      -> P (8KB/head) -> xt f32 lo
//   [32768,65536)   Qbuf bf16[8][64][32] swz((r>>2)&3) -> P hi      -> xt f32 hi
//   [65536,98304)   Kbuf bf16[8][64][32] swz        -> O overlay    -> h2s bf16[64][256] swz
//   [98304,131072)  Vt bf16[8][32][64] swz(d&7)                     -> hid bf16[64][256] swz
#define QB_OFF  32768
#define KB_OFF  65536
#define VT_OFF  98304
#define H2_OFF  65536
#define HID_OFF 98304
#define BLK_LDS 131072

__global__ __launch_bounds__(1024,1) void k_block(
    const float* __restrict__ x,
    const u16* __restrict__ wqkv,  const float* __restrict__ bqkv,
    const u16* __restrict__ wproj, const float* __restrict__ bproj,
    const float* __restrict__ biasT,
    const float* __restrict__ g1, const float* __restrict__ bt1,
    const u16* __restrict__ w1, const float* __restrict__ b1v,
    const u16* __restrict__ w2, const float* __restrict__ b2v,
    const float* __restrict__ g2, const float* __restrict__ bt2,
    float* __restrict__ xg)
{
  extern __shared__ char lds[];
  const int tid = threadIdx.x;
  const int wv = tid >> 6, l = tid & 63;
  const int lr = l & 15, lg = l >> 4;
  const unsigned swzA = ((unsigned)(lr & 7)) << 4;       // 512B/128B-row buffers
  const unsigned swzR = ((unsigned)((lr>>2) & 3)) << 4;  // 64B-row buffers (Q,K,O)
  const int win = blockIdx.x;
  const int bb = win >> 6, wh = (win >> 3) & 7, ww = win & 7;
  const float* xwin = x + (size_t)bb*802816 + (size_t)wh*392 + ww*7;
  const size_t obase = (size_t)bb*802816 + (size_t)wh*392 + ww*7;

  // ---- phase 0: gather + LN1 -> h_s; zero h_s pads and Vt ----
  {
    float gg[4], bgm[4];
    #pragma unroll
    for(int k2=0;k2<4;++k2){ gg[k2]=g1[l+64*k2]; bgm[k2]=bt1[l+64*k2]; }
    float xv[4][4];
    #pragma unroll
    for(int s=0;s<4;++s){
      int n = wv + s*16;
      if(n<49){
        int ii=n/7, jj=n-ii*7;
        const float* px = xwin + ii*56 + jj;
        #pragma unroll
        for(int k2=0;k2<4;++k2) xv[s][k2] = px[(size_t)(l+64*k2)*3136];
      }
    }
    #pragma unroll
    for(int s=0;s<4;++s){
      int n = wv + s*16;
      if(n<49){
        float sm=0.f, sq=0.f;
        #pragma unroll
        for(int k2=0;k2<4;++k2){ sm+=xv[s][k2]; sq+=xv[s][k2]*xv[s][k2]; }
        #pragma unroll
        for(int off=32;off>=1;off>>=1){ sm+=__shfl_xor(sm,off); sq+=__shfl_xor(sq,off); }
        float mu=sm*(1.f/256.f), var=sq*(1.f/256.f)-mu*mu;
        float rs=rsqrtf(var+1e-5f);
        #pragma unroll
        for(int k2=0;k2<4;++k2){
          int c=l+64*k2;
          unsigned off2 = (((unsigned)n)*512u + ((unsigned)c)*2u) ^ (((unsigned)(n&7))<<4);
          *(u16*)(lds + off2) = f2b((xv[s][k2]-mu)*rs*gg[k2]+bgm[k2]);
        }
      }
    }
  }
  for(int m=tid; m<3840; m+=1024) *(u16*)(lds + 49*512 + m*2) = 0;
  for(int m=tid; m<8192; m+=1024) *(unsigned*)(lds + VT_OFF + m*4) = 0u;
  __syncthreads();

  // ---- phase 1: QKV GEMM (transposed D[c][r]); scatter to Qbuf/Kbuf/Vt ----
  for(int ct=wv; ct<48; ct+=16){
    bf16x8 bfr[8];
    const u16* wrow = wqkv + ((size_t)(ct*16+lr))*256 + lg*8;
    #pragma unroll
    for(int k=0;k<8;++k) bfr[k] = *(const bf16x8*)(wrow + k*32);
    f32x4 b4 = *(const f32x4*)(bqkv + ct*16 + lg*4);
    const int s3 = ct>>4, hd = (ct>>1)&7, db = (ct&1)*16 + lg*4;
    #pragma unroll
    for(int rt=0; rt<4; ++rt){
      f32x4 acc = {0.f,0.f,0.f,0.f};
      #pragma unroll
      for(int k=0;k<8;++k){
        bf16x8 afr = *(const bf16x8*)(lds + ((((unsigned)(rt*16+lr))*512u + (unsigned)(k*64+lg*16)) ^ swzA));
        acc = __builtin_amdgcn_mfma_f32_16x16x32_bf16(bfr[k], afr, acc, 0,0,0);
      }
      const int r = rt*16 + lr;
      if(r<49){
        if(s3==0){
          s16x4 pk;
          #pragma unroll
          for(int i=0;i<4;++i) pk[i] = (short)f2b((acc[i]+b4[i])*0.35355339059327373f);
          *(s16x4*)(lds + ((unsigned)(QB_OFF + hd*4096 + r*64 + db*2) ^ swzR)) = pk;
        } else if(s3==1){
          s16x4 pk;
          #pragma unroll
          for(int i=0;i<4;++i) pk[i] = (short)f2b(acc[i]+b4[i]);
          *(s16x4*)(lds + ((unsigned)(KB_OFF + hd*4096 + r*64 + db*2) ^ swzR)) = pk;
        } else {
          #pragma unroll
          for(int i=0;i<4;++i)
            *(u16*)(lds + ((unsigned)(VT_OFF + hd*4096 + (db+i)*128 + r*2) ^ ((((unsigned)(db+i))&7u)<<4))) = f2b(acc[i]+b4[i]);
        }
      }
    }
  }
  __syncthreads();

  // ---- phase 2: attention; 2 waves per head (qt halves) ----
  {
    const int h = wv & 7, half = wv >> 3;
    bf16x8 kf[4], qf[2];
    #pragma unroll
    for(int t=0;t<4;++t)
      kf[t] = *(const bf16x8*)(lds + ((unsigned)(KB_OFF + h*4096 + (t*16+lr)*64 + lg*16) ^ swzR));
    #pragma unroll
    for(int j=0;j<2;++j){
      int qt = half*2 + j;
      qf[j] = *(const bf16x8*)(lds + ((unsigned)(QB_OFF + h*4096 + (qt*16+lr)*64 + lg*16) ^ swzR));
    }
    f32x4 st[2][4];
    #pragma unroll
    for(int j=0;j<2;++j){
      const int qt = half*2 + j;
      #pragma unroll
      for(int kt=0;kt<4;++kt){
        f32x4 bini;
        #pragma unroll
        for(int i=0;i<4;++i) bini[i] = biasT[h*4096 + (kt*16+lg*4+i)*64 + qt*16+lr];
        st[j][kt] = __builtin_amdgcn_mfma_f32_16x16x32_bf16(kf[kt], qf[j], bini, 0,0,0);
      }
    }
    #pragma unroll
    for(int j=0;j<2;++j)
      #pragma unroll
      for(int i=0;i<4;++i)
        if(!(lg==0 && i==0)) st[j][3][i] = -1e30f;   // only k=48 valid in kt=3

    s16x4 pk[2][4];
    #pragma unroll
    for(int j=0;j<2;++j){
      float mx = -1e30f;
      #pragma unroll
      for(int kt=0;kt<4;++kt)
        #pragma unroll
        for(int i=0;i<4;++i) mx = fmaxf(mx, st[j][kt][i]);
      mx = fmaxf(mx, __shfl_xor(mx,16));
      mx = fmaxf(mx, __shfl_xor(mx,32));
      float su = 0.f;
      #pragma unroll
      for(int kt=0;kt<4;++kt)
        #pragma unroll
        for(int i=0;i<4;++i){ float p = __expf(st[j][kt][i]-mx); st[j][kt][i]=p; su+=p; }
      su += __shfl_xor(su,16);
      su += __shfl_xor(su,32);
      float inv = 1.f/su;
      #pragma unroll
      for(int kt=0;kt<4;++kt)
        #pragma unroll
        for(int i=0;i<4;++i) pk[j][kt][i] = (short)f2b(st[j][kt][i]*inv);
    }
    __syncthreads();       // Qbuf/Kbuf reads done -> P may overwrite [0,64K)

    char* Pb = lds + h*8192;
    #pragma unroll
    for(int j=0;j<2;++j){
      const unsigned rq = (unsigned)((half*2+j)*16 + lr);
      #pragma unroll
      for(int kt=0;kt<4;++kt)
        *(s16x4*)(Pb + ((rq*128u + (unsigned)(kt*32+lg*8)) ^ swzA)) = pk[j][kt];
    }
    bf16x8 pf[2][2], vf[2][2];
    #pragma unroll
    for(int j=0;j<2;++j){
      const unsigned rq = (unsigned)((half*2+j)*16 + lr);
      #pragma unroll
      for(int ks=0;ks<2;++ks)
        pf[j][ks] = *(const bf16x8*)(Pb + ((rq*128u + (unsigned)(ks*64+lg*16)) ^ swzA));
    }
    #pragma unroll
    for(int dt=0;dt<2;++dt)
      #pragma unroll
      for(int ks=0;ks<2;++ks)
        vf[dt][ks] = *(const bf16x8*)(lds + ((unsigned)(VT_OFF + h*4096 + (dt*16+lr)*128 + ks*64+lg*16) ^ swzA));
    #pragma unroll
    for(int j=0;j<2;++j){
      const int qt = half*2 + j;
      #pragma unroll
      for(int dt=0;dt<2;++dt){
        f32x4 o = {0.f,0.f,0.f,0.f};
        o = __builtin_amdgcn_mfma_f32_16x16x32_bf16(pf[j][0], vf[dt][0], o, 0,0,0);
        o = __builtin_amdgcn_mfma_f32_16x16x32_bf16(pf[j][1], vf[dt][1], o, 0,0,0);
        #pragma unroll
        for(int i=0;i<4;++i)
          *(u16*)(lds + ((unsigned)(KB_OFF + h*4096 + (qt*16+lg*4+i)*64 + (dt*16+lr)*2) ^ (((unsigned)lg)<<4))) = f2b(o[i]);
      }
    }
  }
  __syncthreads();         // O ready; P dead -> xt may take [0,64K)

  // ---- phase 3: proj GEMM + residual -> xt f32[64][256] at [0,64K) ----
  float* xtf = (float*)lds;
  {
    const int c = wv*16 + lr;
    bf16x8 bfr[8];
    const u16* wrow = wproj + ((size_t)c)*256 + lg*8;
    #pragma unroll
    for(int k=0;k<8;++k) bfr[k] = *(const bf16x8*)(wrow + k*32);
    const float pb = bproj[c];
    #pragma unroll
    for(int mt=0; mt<4; ++mt){
      f32x4 acc = {0.f,0.f,0.f,0.f};
      #pragma unroll
      for(int ks=0;ks<8;++ks){
        bf16x8 afr = *(const bf16x8*)(lds + ((unsigned)(KB_OFF + ks*4096 + (mt*16+lr)*64 + lg*16) ^ swzR));
        acc = __builtin_amdgcn_mfma_f32_16x16x32_bf16(afr, bfr[ks], acc, 0,0,0);
      }
      #pragma unroll
      for(int i=0;i<4;++i){
        int r = mt*16 + lg*4 + i;
        if(r<49){
          int ii=r/7, jj=r-ii*7;
          xtf[r*256 + c] = acc[i] + pb + xwin[(size_t)c*3136 + ii*56 + jj];
        }
      }
    }
  }
  for(int m=tid; m<3840; m+=1024) xtf[49*256+m] = 0.f;   // zero pad rows
  __syncthreads();

  // ---- phase 4: LN2 -> h2s (Kbuf region, O dead) ----
  {
    float gg[4], bb2[4];
    #pragma unroll
    for(int k2=0;k2<4;++k2){ gg[k2]=g2[l+64*k2]; bb2[k2]=bt2[l+64*k2]; }
    #pragma unroll
    for(int rr=0; rr<4; ++rr){
      int r = wv*4 + rr;
      float v[4];
      #pragma unroll
      for(int k2=0;k2<4;++k2) v[k2]=xtf[r*256 + l + 64*k2];
      float sm=v[0]+v[1]+v[2]+v[3];
      float sq=v[0]*v[0]+v[1]*v[1]+v[2]*v[2]+v[3]*v[3];
      #pragma unroll
      for(int off=32;off>=1;off>>=1){ sm+=__shfl_xor(sm,off); sq+=__shfl_xor(sq,off); }
      float mu=sm*(1.f/256.f), var=sq*(1.f/256.f)-mu*mu, rs=rsqrtf(var+1e-5f);
      #pragma unroll
      for(int k2=0;k2<4;++k2){
        int c=l+64*k2;
        unsigned off2 = (unsigned)H2_OFF + ((((unsigned)r)*512u + ((unsigned)c)*2u) ^ (((unsigned)(r&7))<<4));
        *(u16*)(lds + off2) = f2b((v[k2]-mu)*rs*gg[k2]+bb2[k2]);
      }
    }
  }
  __syncthreads();

  // ---- phase 5: MLP, kc chunks of 256 hidden; hid in Vt region ----
  f32x4 acc2[4];
  #pragma unroll
  for(int mt=0;mt<4;++mt) acc2[mt]=(f32x4){0.f,0.f,0.f,0.f};

  for(int kc=0; kc<4; ++kc){
    // GEMM1 + GELU -> hid
    {
      const int hcol = wv*16 + lr;
      const int gcol = kc*256 + hcol;
      bf16x8 bfr[8];
      const u16* wrow = w1 + (size_t)gcol*256 + lg*8;
      #pragma unroll
      for(int k=0;k<8;++k) bfr[k]=*(const bf16x8*)(wrow + k*32);
      const float bias1 = b1v[gcol];
      #pragma unroll
      for(int mt=0; mt<4; ++mt){
        f32x4 acc={0.f,0.f,0.f,0.f};
        #pragma unroll
        for(int k=0;k<8;++k){
          bf16x8 afr = *(const bf16x8*)(lds + (unsigned)H2_OFF + ((((unsigned)(mt*16+lr))*512u + (unsigned)(k*64+lg*16)) ^ swzA));
          acc = __builtin_amdgcn_mfma_f32_16x16x32_bf16(afr, bfr[k], acc, 0,0,0);
        }
        #pragma unroll
        for(int i2=0;i2<4;++i2){
          int r = mt*16 + lg*4 + i2;
          float vv = acc[i2] + bias1;
          float gl = 0.5f*vv*(1.f + erff(vv*0.70710678118654752f));
          unsigned off2 = (unsigned)HID_OFF + ((((unsigned)r)*512u + ((unsigned)hcol)*2u) ^ (((unsigned)(r&7))<<4));
          *(u16*)(lds + off2) = f2b(gl);
        }
      }
    }
    __syncthreads();
    // GEMM2 accumulate
    {
      const int c = wv*16 + lr;
      bf16x8 bfr[8];
      const u16* wrow = w2 + (size_t)c*1024 + kc*256 + lg*8;
      #pragma unroll
      for(int k=0;k<8;++k) bfr[k]=*(const bf16x8*)(wrow + k*32);
      #pragma unroll
      for(int mt=0; mt<4; ++mt){
        f32x4 a4 = acc2[mt];
        #pragma unroll
        for(int k=0;k<8;++k){
          bf16x8 afr = *(const bf16x8*)(lds + (unsigned)HID_OFF + ((((unsigned)(mt*16+lr))*512u + (unsigned)(k*64+lg*16)) ^ swzA));
          a4 = __builtin_amdgcn_mfma_f32_16x16x32_bf16(afr, bfr[k], a4, 0,0,0);
        }
        acc2[mt] = a4;
      }
    }
    __syncthreads();
  }

  // ---- epilogue: +b2 +residual fp32 into xt ----
  {
    const int c = wv*16 + lr;
    const float biasc = b2v[c];
    #pragma unroll
    for(int mt=0; mt<4; ++mt){
      #pragma unroll
      for(int i2=0;i2<4;++i2){
        int r = mt*16 + lg*4 + i2;
        xtf[r*256 + c] = acc2[mt][i2] + biasc + xtf[r*256 + c];
      }
    }
  }
  __syncthreads();

  // ---- writeout fp32 to d_out in [B,C,H,W] layout ----
  for(int u=tid; u<1792; u+=1024){
    int c = u/7, i = u - (u/7)*7;
    float* dst = xg + obase + (size_t)c*3136 + i*56;
    #pragma unroll
    for(int j=0;j<7;++j) dst[j] = xtf[(i*7+j)*256 + c];
  }
}

extern "C" void kernel_launch(void* const* d_in, const int* in_sizes, int n_in,
                              void* d_out, int out_size, void* d_ws, size_t ws_size,
                              hipStream_t stream) {
  const float* x      = (const float*)d_in[0];
  const float* qkv_w  = (const float*)d_in[1];
  const float* qkv_b  = (const float*)d_in[2];
  const float* proj_w = (const float*)d_in[3];
  const float* proj_b = (const float*)d_in[4];
  const float* btab   = (const float*)d_in[5];
  const float* ln1g   = (const float*)d_in[6];
  const float* ln1b   = (const float*)d_in[7];
  const float* ln2g   = (const float*)d_in[8];
  const float* ln2b   = (const float*)d_in[9];
  const float* w1     = (const float*)d_in[10];
  const float* b1     = (const float*)d_in[11];
  const float* w2     = (const float*)d_in[12];
  const float* b2     = (const float*)d_in[13];

  char* ws = (char*)d_ws;
  float* biasT = (float*)ws;                     // 131,072 B
  u16*   wq    = (u16*)(ws + 131072);            // 393,216 B
  u16*   wp    = (u16*)(ws + 524288);            // 131,072 B
  u16*   w1b   = (u16*)(ws + 655360);            // 524,288 B
  u16*   w2b   = (u16*)(ws + 1179648);           // 524,288 B -> total 1,703,936 B

  k_cvt<<<196608/TB, TB, 0, stream>>>(qkv_w, wq, 196608);
  k_cvt<<<65536/TB,  TB, 0, stream>>>(proj_w, wp, 65536);
  k_cvt<<<262144/TB, TB, 0, stream>>>(w1, w1b, 262144);
  k_cvt<<<262144/TB, TB, 0, stream>>>(w2, w2b, 262144);
  k_biasT<<<32768/TB, TB, 0, stream>>>(btab, biasT);

  hipFuncSetAttribute((const void*)k_block, hipFuncAttributeMaxDynamicSharedMemorySize, BLK_LDS);
  k_block<<<2048, 1024, BLK_LDS, stream>>>(x, wq, qkv_b, wp, proj_b, biasT, ln1g, ln1b,
                                           w1b, b1, w2b, b2, ln2g, ln2b, (float*)d_out);
}